// Round 1
// baseline (628.379 us; speedup 1.0000x reference)
//
#include <hip/hip_runtime.h>
#include <math.h>

#define IN_DIM 512
#define EMBED 128
#define OUT_DIM 64

__device__ __forceinline__ float lrelu(float v, float s) { return v > 0.f ? v : v * s; }

// ---------------------------------------------------------------------------
// K1: h[N,128] = leaky_relu(x[N,512] @ Wd[128,512]^T + bd, 0.01)
// BM=64, BN=128, BK=16, 256 threads, 4x8 micro-tile (cols split tx*4 / 64+tx*4
// so LDS reads are 2-way-or-broadcast => conflict-free).
// ---------------------------------------------------------------------------
__global__ __launch_bounds__(256) void gemm1_kernel(
    const float* __restrict__ x, const float* __restrict__ Wd,
    const float* __restrict__ bd, float* __restrict__ h, int N) {
  __shared__ float As[16][68];   // [k][m], 68*4B row => 16B-aligned rows
  __shared__ float Bs[16][132];  // [k][n]
  const int tid = threadIdx.x;
  const int tx = tid & 15, ty = tid >> 4;
  const int mblk = blockIdx.x * 64;

  float acc[4][8];
#pragma unroll
  for (int i = 0; i < 4; ++i)
#pragma unroll
    for (int j = 0; j < 8; ++j) acc[i][j] = 0.f;

  const int arow = tid >> 2, acol = (tid & 3) * 4;  // 64 rows x 16 k
  const int brow = tid >> 1, bcol = (tid & 1) * 8;  // 128 rows x 16 k
  const bool avalid = (mblk + arow) < N;
  const float* aptr = x + (size_t)(mblk + arow) * IN_DIM + acol;
  const float* bptr = Wd + (size_t)brow * IN_DIM + bcol;

  for (int k0 = 0; k0 < IN_DIM; k0 += 16) {
    float4 av = avalid ? *(const float4*)(aptr + k0) : make_float4(0.f, 0.f, 0.f, 0.f);
    float4 bv0 = *(const float4*)(bptr + k0);
    float4 bv1 = *(const float4*)(bptr + k0 + 4);
    __syncthreads();
    As[acol + 0][arow] = av.x;
    As[acol + 1][arow] = av.y;
    As[acol + 2][arow] = av.z;
    As[acol + 3][arow] = av.w;
    Bs[bcol + 0][brow] = bv0.x;
    Bs[bcol + 1][brow] = bv0.y;
    Bs[bcol + 2][brow] = bv0.z;
    Bs[bcol + 3][brow] = bv0.w;
    Bs[bcol + 4][brow] = bv1.x;
    Bs[bcol + 5][brow] = bv1.y;
    Bs[bcol + 6][brow] = bv1.z;
    Bs[bcol + 7][brow] = bv1.w;
    __syncthreads();
#pragma unroll
    for (int k = 0; k < 16; ++k) {
      float4 a = *(const float4*)&As[k][ty * 4];
      float4 b0 = *(const float4*)&Bs[k][tx * 4];
      float4 b1 = *(const float4*)&Bs[k][64 + tx * 4];
      float am[4] = {a.x, a.y, a.z, a.w};
      float bm[8] = {b0.x, b0.y, b0.z, b0.w, b1.x, b1.y, b1.z, b1.w};
#pragma unroll
      for (int i = 0; i < 4; ++i)
#pragma unroll
        for (int j = 0; j < 8; ++j) acc[i][j] += am[i] * bm[j];
    }
  }

  const int c0 = tx * 4;
  float bda[8];
#pragma unroll
  for (int j = 0; j < 4; ++j) {
    bda[j] = bd[c0 + j];
    bda[4 + j] = bd[64 + c0 + j];
  }
#pragma unroll
  for (int i = 0; i < 4; ++i) {
    int m = mblk + ty * 4 + i;
    if (m < N) {
      float4 o0, o1;
      o0.x = lrelu(acc[i][0] + bda[0], 0.01f);
      o0.y = lrelu(acc[i][1] + bda[1], 0.01f);
      o0.z = lrelu(acc[i][2] + bda[2], 0.01f);
      o0.w = lrelu(acc[i][3] + bda[3], 0.01f);
      o1.x = lrelu(acc[i][4] + bda[4], 0.01f);
      o1.y = lrelu(acc[i][5] + bda[5], 0.01f);
      o1.z = lrelu(acc[i][6] + bda[6], 0.01f);
      o1.w = lrelu(acc[i][7] + bda[7], 0.01f);
      *(float4*)&h[(size_t)m * EMBED + c0] = o0;
      *(float4*)&h[(size_t)m * EMBED + 64 + c0] = o1;
    }
  }
}

// ---------------------------------------------------------------------------
// K2: g[N,64] = h[N,128] @ Wg[64,128]^T ; a_src = g@att_src ; a_dst = g@att_dst
// BM=64, BN=64, BK=16, 256 threads, 4x4 micro-tile.
// ---------------------------------------------------------------------------
__global__ __launch_bounds__(256) void gemm2_kernel(
    const float* __restrict__ h, const float* __restrict__ Wg,
    const float* __restrict__ att_src, const float* __restrict__ att_dst,
    float* __restrict__ g, float* __restrict__ a_src, float* __restrict__ a_dst,
    int N) {
  __shared__ float As[16][68];
  __shared__ float Bs[16][68];
  const int tid = threadIdx.x;
  const int tx = tid & 15, ty = tid >> 4;
  const int mblk = blockIdx.x * 64;

  float acc[4][4];
#pragma unroll
  for (int i = 0; i < 4; ++i)
#pragma unroll
    for (int j = 0; j < 4; ++j) acc[i][j] = 0.f;

  const int arow = tid >> 2, acol = (tid & 3) * 4;  // 64 rows x 16 k
  const bool avalid = (mblk + arow) < N;
  const float* aptr = h + (size_t)(mblk + arow) * EMBED + acol;
  const float* bptr = Wg + (size_t)arow * EMBED + acol;  // Wg: 64 rows

  for (int k0 = 0; k0 < EMBED; k0 += 16) {
    float4 av = avalid ? *(const float4*)(aptr + k0) : make_float4(0.f, 0.f, 0.f, 0.f);
    float4 bv = *(const float4*)(bptr + k0);
    __syncthreads();
    As[acol + 0][arow] = av.x;
    As[acol + 1][arow] = av.y;
    As[acol + 2][arow] = av.z;
    As[acol + 3][arow] = av.w;
    Bs[acol + 0][arow] = bv.x;
    Bs[acol + 1][arow] = bv.y;
    Bs[acol + 2][arow] = bv.z;
    Bs[acol + 3][arow] = bv.w;
    __syncthreads();
#pragma unroll
    for (int k = 0; k < 16; ++k) {
      float4 a = *(const float4*)&As[k][ty * 4];
      float4 b = *(const float4*)&Bs[k][tx * 4];
      float am[4] = {a.x, a.y, a.z, a.w};
      float bm[4] = {b.x, b.y, b.z, b.w};
#pragma unroll
      for (int i = 0; i < 4; ++i)
#pragma unroll
        for (int j = 0; j < 4; ++j) acc[i][j] += am[i] * bm[j];
    }
  }

  const int c0 = tx * 4;
  float as_[4], ad_[4];
#pragma unroll
  for (int j = 0; j < 4; ++j) {
    as_[j] = att_src[c0 + j];
    ad_[j] = att_dst[c0 + j];
  }
#pragma unroll
  for (int i = 0; i < 4; ++i) {
    int m = mblk + ty * 4 + i;
    float ps = acc[i][0] * as_[0] + acc[i][1] * as_[1] + acc[i][2] * as_[2] + acc[i][3] * as_[3];
    float pd = acc[i][0] * ad_[0] + acc[i][1] * ad_[1] + acc[i][2] * ad_[2] + acc[i][3] * ad_[3];
#pragma unroll
    for (int d = 1; d < 16; d <<= 1) {
      ps += __shfl_xor(ps, d, 64);
      pd += __shfl_xor(pd, d, 64);
    }
    if (m < N) {
      *(float4*)&g[(size_t)m * OUT_DIM + c0] =
          make_float4(acc[i][0], acc[i][1], acc[i][2], acc[i][3]);
      if (tx == 0) {
        a_src[m] = ps;
        a_dst[m] = pd;
      }
    }
  }
}

// ---------------------------------------------------------------------------
// Edge-phase kernels: CSR build by dst, then per-node online softmax.
// ---------------------------------------------------------------------------
__global__ void zero_kernel(int* __restrict__ p, int n) {
  int i = blockIdx.x * blockDim.x + threadIdx.x;
  if (i < n) p[i] = 0;
}

__global__ void hist_kernel(const int* __restrict__ ei, int* __restrict__ counts,
                            int E, int N) {
  int i = blockIdx.x * blockDim.x + threadIdx.x;
  if (i < E + N) {
    int d = (i < E) ? ei[E + i] : (i - E);
    atomicAdd(&counts[d], 1);
  }
}

// single-block exclusive scan (1024 threads, shuffle-based)
__global__ __launch_bounds__(1024) void scan_kernel(const int* __restrict__ counts,
                                                    int* __restrict__ offsets,
                                                    int* __restrict__ next, int n) {
  __shared__ int warp_tot[16];
  __shared__ int warp_scan[16];
  const int tid = threadIdx.x;
  const int lane = tid & 63, w = tid >> 6;
  int carry = 0;
  for (int base = 0; base < n; base += 1024) {
    int i = base + tid;
    int v = (i < n) ? counts[i] : 0;
    int incl = v;
#pragma unroll
    for (int d = 1; d < 64; d <<= 1) {
      int t = __shfl_up(incl, d, 64);
      if (lane >= d) incl += t;
    }
    if (lane == 63) warp_tot[w] = incl;
    __syncthreads();
    if (w == 0) {
      int sc = (lane < 16) ? warp_tot[lane] : 0;
#pragma unroll
      for (int d = 1; d < 16; d <<= 1) {
        int u = __shfl_up(sc, d, 64);
        if (lane >= d) sc += u;
      }
      if (lane < 16) warp_scan[lane] = sc;
    }
    __syncthreads();
    int woff = (w > 0) ? warp_scan[w - 1] : 0;
    int excl = carry + woff + incl - v;
    if (i < n) {
      offsets[i] = excl;
      next[i] = excl;
    }
    carry += warp_scan[15];
    __syncthreads();
  }
  if (tid == 0) offsets[n] = carry;
}

__global__ void scatter_kernel(const int* __restrict__ ei,
                               const float* __restrict__ a_src,
                               const float* __restrict__ a_dst,
                               int* __restrict__ next, int* __restrict__ csr_src,
                               float* __restrict__ csr_e, int E, int N) {
  int i = blockIdx.x * blockDim.x + threadIdx.x;
  if (i < E + N) {
    int s, d;
    if (i < E) {
      s = ei[i];
      d = ei[E + i];
    } else {
      s = d = i - E;
    }
    float e = a_src[s] + a_dst[d];
    e = e > 0.f ? e : 0.2f * e;  // leaky_relu(0.2)
    int pos = atomicAdd(&next[d], 1);
    csr_src[pos] = s;
    csr_e[pos] = e;
  }
}

// one wave per node, lane = output dim, online softmax
__global__ __launch_bounds__(256) void aggregate_kernel(
    const int* __restrict__ offsets, const int* __restrict__ csr_src,
    const float* __restrict__ csr_e, const float* __restrict__ g,
    const float* __restrict__ b_gat, float* __restrict__ out, int N) {
  const int lane = threadIdx.x & 63;
  const int node = blockIdx.x * 4 + (threadIdx.x >> 6);
  if (node >= N) return;
  const int beg = offsets[node], end = offsets[node + 1];
  const float bg = b_gat[lane];
  float m = -1e30f, l = 0.f, acc = 0.f;
  for (int j = beg; j < end; ++j) {
    float e = csr_e[j];
    int s = csr_src[j];
    float gv = g[(size_t)s * OUT_DIM + lane];
    float mn = fmaxf(m, e);
    float scale = __expf(m - mn);
    float p = __expf(e - mn);
    l = l * scale + p;
    acc = acc * scale + p * gv;
    m = mn;
  }
  out[(size_t)node * OUT_DIM + lane] = acc / l + bg;
}

// ---------------------------------------------------------------------------
extern "C" void kernel_launch(void* const* d_in, const int* in_sizes, int n_in,
                              void* d_out, int out_size, void* d_ws, size_t ws_size,
                              hipStream_t stream) {
  const float* x = (const float*)d_in[0];
  const int* ei = (const int*)d_in[1];
  const float* Wd = (const float*)d_in[2];
  const float* bd = (const float*)d_in[3];
  const float* Wg = (const float*)d_in[4];
  const float* att_src = (const float*)d_in[5];
  const float* att_dst = (const float*)d_in[6];
  const float* bg = (const float*)d_in[7];
  float* out = (float*)d_out;

  const int N = in_sizes[0] / IN_DIM;
  const int E = in_sizes[1] / 2;
  const int T = E + N;

  char* ws = (char*)d_ws;
  size_t off = 0;
  auto alloc = [&](size_t bytes) -> void* {
    void* p = ws + off;
    off += (bytes + 15) & ~(size_t)15;
    return p;
  };
  float* h = (float*)alloc((size_t)N * EMBED * 4);       // 25.6 MB
  float* g = (float*)alloc((size_t)N * OUT_DIM * 4);     // 12.8 MB
  float* a_src = (float*)alloc((size_t)N * 4);
  float* a_dst = (float*)alloc((size_t)N * 4);
  int* counts = (int*)alloc((size_t)N * 4);
  int* offsets = (int*)alloc((size_t)(N + 1) * 4);
  int* next = (int*)alloc((size_t)N * 4);
  int* csr_src = (int*)alloc((size_t)T * 4);             // 6.6 MB
  float* csr_e = (float*)alloc((size_t)T * 4);           // 6.6 MB

  hipLaunchKernelGGL(gemm1_kernel, dim3((N + 63) / 64), dim3(256), 0, stream,
                     x, Wd, bd, h, N);
  hipLaunchKernelGGL(gemm2_kernel, dim3((N + 63) / 64), dim3(256), 0, stream,
                     h, Wg, att_src, att_dst, g, a_src, a_dst, N);
  hipLaunchKernelGGL(zero_kernel, dim3((N + 255) / 256), dim3(256), 0, stream,
                     counts, N);
  hipLaunchKernelGGL(hist_kernel, dim3((T + 255) / 256), dim3(256), 0, stream,
                     ei, counts, E, N);
  hipLaunchKernelGGL(scan_kernel, dim3(1), dim3(1024), 0, stream,
                     counts, offsets, next, N);
  hipLaunchKernelGGL(scatter_kernel, dim3((T + 255) / 256), dim3(256), 0, stream,
                     ei, a_src, a_dst, next, csr_src, csr_e, E, N);
  hipLaunchKernelGGL(aggregate_kernel, dim3((N + 3) / 4), dim3(256), 0, stream,
                     offsets, csr_src, csr_e, g, bg, out, N);
}

// Round 2
// 512.425 us; speedup vs baseline: 1.2263x; 1.2263x over previous
//
#include <hip/hip_runtime.h>
#include <math.h>

#define IN_DIM 512
#define EMBED 128
#define OUT_DIM 64

__device__ __forceinline__ float lrelu(float v, float s) { return v > 0.f ? v : v * s; }

__device__ __forceinline__ float readlane_f(float v, int l) {
  return __int_as_float(__builtin_amdgcn_readlane(__float_as_int(v), l));
}

// ---------------------------------------------------------------------------
// K1: h[N,128] = leaky_relu(x[N,512] @ Wd[128,512]^T + bd, 0.01)
// ---------------------------------------------------------------------------
__global__ __launch_bounds__(256) void gemm1_kernel(
    const float* __restrict__ x, const float* __restrict__ Wd,
    const float* __restrict__ bd, float* __restrict__ h, int N) {
  __shared__ float As[16][68];   // [k][m]
  __shared__ float Bs[16][132];  // [k][n]
  const int tid = threadIdx.x;
  const int tx = tid & 15, ty = tid >> 4;
  const int mblk = blockIdx.x * 64;

  float acc[4][8];
#pragma unroll
  for (int i = 0; i < 4; ++i)
#pragma unroll
    for (int j = 0; j < 8; ++j) acc[i][j] = 0.f;

  const int arow = tid >> 2, acol = (tid & 3) * 4;
  const int brow = tid >> 1, bcol = (tid & 1) * 8;
  const bool avalid = (mblk + arow) < N;
  const float* aptr = x + (size_t)(mblk + arow) * IN_DIM + acol;
  const float* bptr = Wd + (size_t)brow * IN_DIM + bcol;

  for (int k0 = 0; k0 < IN_DIM; k0 += 16) {
    float4 av = avalid ? *(const float4*)(aptr + k0) : make_float4(0.f, 0.f, 0.f, 0.f);
    float4 bv0 = *(const float4*)(bptr + k0);
    float4 bv1 = *(const float4*)(bptr + k0 + 4);
    __syncthreads();
    As[acol + 0][arow] = av.x;
    As[acol + 1][arow] = av.y;
    As[acol + 2][arow] = av.z;
    As[acol + 3][arow] = av.w;
    Bs[bcol + 0][brow] = bv0.x;
    Bs[bcol + 1][brow] = bv0.y;
    Bs[bcol + 2][brow] = bv0.z;
    Bs[bcol + 3][brow] = bv0.w;
    Bs[bcol + 4][brow] = bv1.x;
    Bs[bcol + 5][brow] = bv1.y;
    Bs[bcol + 6][brow] = bv1.z;
    Bs[bcol + 7][brow] = bv1.w;
    __syncthreads();
#pragma unroll
    for (int k = 0; k < 16; ++k) {
      float4 a = *(const float4*)&As[k][ty * 4];
      float4 b0 = *(const float4*)&Bs[k][tx * 4];
      float4 b1 = *(const float4*)&Bs[k][64 + tx * 4];
      float am[4] = {a.x, a.y, a.z, a.w};
      float bm[8] = {b0.x, b0.y, b0.z, b0.w, b1.x, b1.y, b1.z, b1.w};
#pragma unroll
      for (int i = 0; i < 4; ++i)
#pragma unroll
        for (int j = 0; j < 8; ++j) acc[i][j] += am[i] * bm[j];
    }
  }

  const int c0 = tx * 4;
  float bda[8];
#pragma unroll
  for (int j = 0; j < 4; ++j) {
    bda[j] = bd[c0 + j];
    bda[4 + j] = bd[64 + c0 + j];
  }
#pragma unroll
  for (int i = 0; i < 4; ++i) {
    int m = mblk + ty * 4 + i;
    if (m < N) {
      float4 o0, o1;
      o0.x = lrelu(acc[i][0] + bda[0], 0.01f);
      o0.y = lrelu(acc[i][1] + bda[1], 0.01f);
      o0.z = lrelu(acc[i][2] + bda[2], 0.01f);
      o0.w = lrelu(acc[i][3] + bda[3], 0.01f);
      o1.x = lrelu(acc[i][4] + bda[4], 0.01f);
      o1.y = lrelu(acc[i][5] + bda[5], 0.01f);
      o1.z = lrelu(acc[i][6] + bda[6], 0.01f);
      o1.w = lrelu(acc[i][7] + bda[7], 0.01f);
      *(float4*)&h[(size_t)m * EMBED + c0] = o0;
      *(float4*)&h[(size_t)m * EMBED + 64 + c0] = o1;
    }
  }
}

// ---------------------------------------------------------------------------
// K2: g = h @ Wg^T ; a_src = g@att_src ; a_dst = g@att_dst
// ---------------------------------------------------------------------------
__global__ __launch_bounds__(256) void gemm2_kernel(
    const float* __restrict__ h, const float* __restrict__ Wg,
    const float* __restrict__ att_src, const float* __restrict__ att_dst,
    float* __restrict__ g, float* __restrict__ a_src, float* __restrict__ a_dst,
    int N) {
  __shared__ float As[16][68];
  __shared__ float Bs[16][68];
  const int tid = threadIdx.x;
  const int tx = tid & 15, ty = tid >> 4;
  const int mblk = blockIdx.x * 64;

  float acc[4][4];
#pragma unroll
  for (int i = 0; i < 4; ++i)
#pragma unroll
    for (int j = 0; j < 4; ++j) acc[i][j] = 0.f;

  const int arow = tid >> 2, acol = (tid & 3) * 4;
  const bool avalid = (mblk + arow) < N;
  const float* aptr = h + (size_t)(mblk + arow) * EMBED + acol;
  const float* bptr = Wg + (size_t)arow * EMBED + acol;

  for (int k0 = 0; k0 < EMBED; k0 += 16) {
    float4 av = avalid ? *(const float4*)(aptr + k0) : make_float4(0.f, 0.f, 0.f, 0.f);
    float4 bv = *(const float4*)(bptr + k0);
    __syncthreads();
    As[acol + 0][arow] = av.x;
    As[acol + 1][arow] = av.y;
    As[acol + 2][arow] = av.z;
    As[acol + 3][arow] = av.w;
    Bs[acol + 0][arow] = bv.x;
    Bs[acol + 1][arow] = bv.y;
    Bs[acol + 2][arow] = bv.z;
    Bs[acol + 3][arow] = bv.w;
    __syncthreads();
#pragma unroll
    for (int k = 0; k < 16; ++k) {
      float4 a = *(const float4*)&As[k][ty * 4];
      float4 b = *(const float4*)&Bs[k][tx * 4];
      float am[4] = {a.x, a.y, a.z, a.w};
      float bm[4] = {b.x, b.y, b.z, b.w};
#pragma unroll
      for (int i = 0; i < 4; ++i)
#pragma unroll
        for (int j = 0; j < 4; ++j) acc[i][j] += am[i] * bm[j];
    }
  }

  const int c0 = tx * 4;
  float as_[4], ad_[4];
#pragma unroll
  for (int j = 0; j < 4; ++j) {
    as_[j] = att_src[c0 + j];
    ad_[j] = att_dst[c0 + j];
  }
#pragma unroll
  for (int i = 0; i < 4; ++i) {
    int m = mblk + ty * 4 + i;
    float ps = acc[i][0] * as_[0] + acc[i][1] * as_[1] + acc[i][2] * as_[2] + acc[i][3] * as_[3];
    float pd = acc[i][0] * ad_[0] + acc[i][1] * ad_[1] + acc[i][2] * ad_[2] + acc[i][3] * ad_[3];
#pragma unroll
    for (int d = 1; d < 16; d <<= 1) {
      ps += __shfl_xor(ps, d, 64);
      pd += __shfl_xor(pd, d, 64);
    }
    if (m < N) {
      *(float4*)&g[(size_t)m * OUT_DIM + c0] =
          make_float4(acc[i][0], acc[i][1], acc[i][2], acc[i][3]);
      if (tx == 0) {
        a_src[m] = ps;
        a_dst[m] = pd;
      }
    }
  }
}

// ---------------------------------------------------------------------------
// Edge-phase kernels
// ---------------------------------------------------------------------------
__global__ void zero_kernel(int* __restrict__ p, int n) {
  int i = blockIdx.x * blockDim.x + threadIdx.x;
  if (i < n) p[i] = 0;
}

__global__ void hist_kernel(const int* __restrict__ ei, int* __restrict__ counts,
                            int E, int N) {
  int i = blockIdx.x * blockDim.x + threadIdx.x;
  if (i < E + N) {
    int d = (i < E) ? ei[E + i] : (i - E);
    atomicAdd(&counts[d], 1);
  }
}

// single-block exclusive scan, int4 per thread (4096 elems/iter)
__global__ __launch_bounds__(1024) void scan_kernel(const int4* __restrict__ counts4,
                                                    int* __restrict__ offsets,
                                                    int* __restrict__ next,
                                                    int n4, int n) {
  __shared__ int warp_tot[16];
  __shared__ int warp_scan[16];
  const int tid = threadIdx.x;
  const int lane = tid & 63, w = tid >> 6;
  int carry = 0;
  for (int base = 0; base < n4; base += 1024) {
    int i = base + tid;
    int4 v = (i < n4) ? counts4[i] : make_int4(0, 0, 0, 0);
    int t0 = v.x, t1 = t0 + v.y, t2 = t1 + v.z, t3 = t2 + v.w;
    int incl = t3;
#pragma unroll
    for (int d = 1; d < 64; d <<= 1) {
      int t = __shfl_up(incl, d, 64);
      if (lane >= d) incl += t;
    }
    if (lane == 63) warp_tot[w] = incl;
    __syncthreads();
    if (w == 0) {
      int sc = (lane < 16) ? warp_tot[lane] : 0;
#pragma unroll
      for (int d = 1; d < 16; d <<= 1) {
        int u = __shfl_up(sc, d, 64);
        if (lane >= d) sc += u;
      }
      if (lane < 16) warp_scan[lane] = sc;
    }
    __syncthreads();
    int woff = (w > 0) ? warp_scan[w - 1] : 0;
    int excl = carry + woff + incl - t3;
    if (i < n4) {
      int4 o = make_int4(excl, excl + t0, excl + t1, excl + t2);
      *(int4*)&offsets[4 * i] = o;
      *(int4*)&next[4 * i] = o;
    }
    carry += warp_scan[15];
    __syncthreads();
  }
  if (tid == 0) offsets[n] = carry;
}

__global__ void scatter_kernel(const int* __restrict__ ei,
                               const float* __restrict__ a_src,
                               const float* __restrict__ a_dst,
                               int* __restrict__ next, int* __restrict__ csr_src,
                               float* __restrict__ csr_e, int E, int N) {
  int i = blockIdx.x * blockDim.x + threadIdx.x;
  if (i < E + N) {
    int s, d;
    if (i < E) {
      s = ei[i];
      d = ei[E + i];
    } else {
      s = d = i - E;
    }
    float e = a_src[s] + a_dst[d];
    e = e > 0.f ? e : 0.2f * e;  // leaky_relu(0.2)
    int pos = atomicAdd(&next[d], 1);
    csr_src[pos] = s;
    csr_e[pos] = e;
  }
}

// ---------------------------------------------------------------------------
// one wave per node, lane = output dim.
// Pass 1/2: lane-parallel max & denom over the node's edges.
// Pass 3: chunk-of-64 — lane j holds alpha_j/src_j, broadcast via readlane;
// 4 independent accumulators break the FMA chain.
// ---------------------------------------------------------------------------
__global__ __launch_bounds__(256) void aggregate_kernel(
    const int* __restrict__ offsets, const int* __restrict__ csr_src,
    const float* __restrict__ csr_e, const float* __restrict__ g,
    const float* __restrict__ b_gat, float* __restrict__ out, int N) {
  const int lane = threadIdx.x & 63;
  const int node = blockIdx.x * 4 + (threadIdx.x >> 6);
  if (node >= N) return;
  const int beg = offsets[node], end = offsets[node + 1];

  // pass 1: max
  float m = -1e30f;
  for (int j = beg + lane; j < end; j += 64) m = fmaxf(m, csr_e[j]);
#pragma unroll
  for (int d = 1; d < 64; d <<= 1) m = fmaxf(m, __shfl_xor(m, d, 64));

  // pass 2: denom
  float l = 0.f;
  for (int j = beg + lane; j < end; j += 64) l += __expf(csr_e[j] - m);
#pragma unroll
  for (int d = 1; d < 64; d <<= 1) l += __shfl_xor(l, d, 64);
  const float inv_l = 1.f / l;

  // pass 3: aggregate
  float acc0 = 0.f, acc1 = 0.f, acc2 = 0.f, acc3 = 0.f;
  for (int jb = beg; jb < end; jb += 64) {
    int j = jb + lane;
    float p = 0.f;
    int s = 0;
    if (j < end) {
      p = __expf(csr_e[j] - m) * inv_l;
      s = csr_src[j];
    }
    const int cnt = min(64, end - jb);
    int jj = 0;
    for (; jj + 4 <= cnt; jj += 4) {
      int s0 = __builtin_amdgcn_readlane(s, jj);
      int s1 = __builtin_amdgcn_readlane(s, jj + 1);
      int s2 = __builtin_amdgcn_readlane(s, jj + 2);
      int s3 = __builtin_amdgcn_readlane(s, jj + 3);
      float p0 = readlane_f(p, jj);
      float p1 = readlane_f(p, jj + 1);
      float p2 = readlane_f(p, jj + 2);
      float p3 = readlane_f(p, jj + 3);
      acc0 += p0 * g[((size_t)s0 << 6) + lane];
      acc1 += p1 * g[((size_t)s1 << 6) + lane];
      acc2 += p2 * g[((size_t)s2 << 6) + lane];
      acc3 += p3 * g[((size_t)s3 << 6) + lane];
    }
    for (; jj < cnt; ++jj) {
      int s0 = __builtin_amdgcn_readlane(s, jj);
      float p0 = readlane_f(p, jj);
      acc0 += p0 * g[((size_t)s0 << 6) + lane];
    }
  }
  out[(size_t)node * OUT_DIM + lane] = (acc0 + acc1) + (acc2 + acc3) + b_gat[lane];
}

// ---------------------------------------------------------------------------
extern "C" void kernel_launch(void* const* d_in, const int* in_sizes, int n_in,
                              void* d_out, int out_size, void* d_ws, size_t ws_size,
                              hipStream_t stream) {
  const float* x = (const float*)d_in[0];
  const int* ei = (const int*)d_in[1];
  const float* Wd = (const float*)d_in[2];
  const float* bd = (const float*)d_in[3];
  const float* Wg = (const float*)d_in[4];
  const float* att_src = (const float*)d_in[5];
  const float* att_dst = (const float*)d_in[6];
  const float* bg = (const float*)d_in[7];
  float* out = (float*)d_out;

  const int N = in_sizes[0] / IN_DIM;
  const int E = in_sizes[1] / 2;
  const int T = E + N;

  char* ws = (char*)d_ws;
  size_t off = 0;
  auto alloc = [&](size_t bytes) -> void* {
    void* p = ws + off;
    off += (bytes + 15) & ~(size_t)15;
    return p;
  };
  float* h = (float*)alloc((size_t)N * EMBED * 4);
  float* g = (float*)alloc((size_t)N * OUT_DIM * 4);
  float* a_src = (float*)alloc((size_t)N * 4);
  float* a_dst = (float*)alloc((size_t)N * 4);
  int* counts = (int*)alloc((size_t)N * 4);
  int* offsets = (int*)alloc((size_t)(N + 1) * 4);
  int* next = (int*)alloc((size_t)N * 4);
  int* csr_src = (int*)alloc((size_t)T * 4);
  float* csr_e = (float*)alloc((size_t)T * 4);

  hipLaunchKernelGGL(gemm1_kernel, dim3((N + 63) / 64), dim3(256), 0, stream,
                     x, Wd, bd, h, N);
  hipLaunchKernelGGL(gemm2_kernel, dim3((N + 63) / 64), dim3(256), 0, stream,
                     h, Wg, att_src, att_dst, g, a_src, a_dst, N);
  hipLaunchKernelGGL(zero_kernel, dim3((N + 255) / 256), dim3(256), 0, stream,
                     counts, N);
  hipLaunchKernelGGL(hist_kernel, dim3((T + 255) / 256), dim3(256), 0, stream,
                     ei, counts, E, N);
  hipLaunchKernelGGL(scan_kernel, dim3(1), dim3(1024), 0, stream,
                     (const int4*)counts, offsets, next, N / 4, N);
  hipLaunchKernelGGL(scatter_kernel, dim3((T + 255) / 256), dim3(256), 0, stream,
                     ei, a_src, a_dst, next, csr_src, csr_e, E, N);
  hipLaunchKernelGGL(aggregate_kernel, dim3((N + 3) / 4), dim3(256), 0, stream,
                     offsets, csr_src, csr_e, g, bg, out, N);
}

// Round 3
// 483.423 us; speedup vs baseline: 1.2999x; 1.0600x over previous
//
#include <hip/hip_runtime.h>
#include <math.h>

#define IN_DIM 512
#define EMBED 128
#define OUT_DIM 64

__device__ __forceinline__ float lrelu(float v, float s) { return v > 0.f ? v : v * s; }

__device__ __forceinline__ float readlane_f(float v, int l) {
  return __int_as_float(__builtin_amdgcn_readlane(__float_as_int(v), l));
}

// ---------------------------------------------------------------------------
// K1: h[N,128] = leaky_relu(x[N,512] @ Wd[128,512]^T + bd, 0.01)
// ---------------------------------------------------------------------------
__global__ __launch_bounds__(256) void gemm1_kernel(
    const float* __restrict__ x, const float* __restrict__ Wd,
    const float* __restrict__ bd, float* __restrict__ h, int N) {
  __shared__ float As[16][68];   // [k][m]
  __shared__ float Bs[16][132];  // [k][n]
  const int tid = threadIdx.x;
  const int tx = tid & 15, ty = tid >> 4;
  const int mblk = blockIdx.x * 64;

  float acc[4][8];
#pragma unroll
  for (int i = 0; i < 4; ++i)
#pragma unroll
    for (int j = 0; j < 8; ++j) acc[i][j] = 0.f;

  const int arow = tid >> 2, acol = (tid & 3) * 4;
  const int brow = tid >> 1, bcol = (tid & 1) * 8;
  const bool avalid = (mblk + arow) < N;
  const float* aptr = x + (size_t)(mblk + arow) * IN_DIM + acol;
  const float* bptr = Wd + (size_t)brow * IN_DIM + bcol;

  for (int k0 = 0; k0 < IN_DIM; k0 += 16) {
    float4 av = avalid ? *(const float4*)(aptr + k0) : make_float4(0.f, 0.f, 0.f, 0.f);
    float4 bv0 = *(const float4*)(bptr + k0);
    float4 bv1 = *(const float4*)(bptr + k0 + 4);
    __syncthreads();
    As[acol + 0][arow] = av.x;
    As[acol + 1][arow] = av.y;
    As[acol + 2][arow] = av.z;
    As[acol + 3][arow] = av.w;
    Bs[bcol + 0][brow] = bv0.x;
    Bs[bcol + 1][brow] = bv0.y;
    Bs[bcol + 2][brow] = bv0.z;
    Bs[bcol + 3][brow] = bv0.w;
    Bs[bcol + 4][brow] = bv1.x;
    Bs[bcol + 5][brow] = bv1.y;
    Bs[bcol + 6][brow] = bv1.z;
    Bs[bcol + 7][brow] = bv1.w;
    __syncthreads();
#pragma unroll
    for (int k = 0; k < 16; ++k) {
      float4 a = *(const float4*)&As[k][ty * 4];
      float4 b0 = *(const float4*)&Bs[k][tx * 4];
      float4 b1 = *(const float4*)&Bs[k][64 + tx * 4];
      float am[4] = {a.x, a.y, a.z, a.w};
      float bm[8] = {b0.x, b0.y, b0.z, b0.w, b1.x, b1.y, b1.z, b1.w};
#pragma unroll
      for (int i = 0; i < 4; ++i)
#pragma unroll
        for (int j = 0; j < 8; ++j) acc[i][j] += am[i] * bm[j];
    }
  }

  const int c0 = tx * 4;
  float bda[8];
#pragma unroll
  for (int j = 0; j < 4; ++j) {
    bda[j] = bd[c0 + j];
    bda[4 + j] = bd[64 + c0 + j];
  }
#pragma unroll
  for (int i = 0; i < 4; ++i) {
    int m = mblk + ty * 4 + i;
    if (m < N) {
      float4 o0, o1;
      o0.x = lrelu(acc[i][0] + bda[0], 0.01f);
      o0.y = lrelu(acc[i][1] + bda[1], 0.01f);
      o0.z = lrelu(acc[i][2] + bda[2], 0.01f);
      o0.w = lrelu(acc[i][3] + bda[3], 0.01f);
      o1.x = lrelu(acc[i][4] + bda[4], 0.01f);
      o1.y = lrelu(acc[i][5] + bda[5], 0.01f);
      o1.z = lrelu(acc[i][6] + bda[6], 0.01f);
      o1.w = lrelu(acc[i][7] + bda[7], 0.01f);
      *(float4*)&h[(size_t)m * EMBED + c0] = o0;
      *(float4*)&h[(size_t)m * EMBED + 64 + c0] = o1;
    }
  }
}

// ---------------------------------------------------------------------------
// K2: g = h @ Wg^T ; a_src = g@att_src ; a_dst = g@att_dst
// ---------------------------------------------------------------------------
__global__ __launch_bounds__(256) void gemm2_kernel(
    const float* __restrict__ h, const float* __restrict__ Wg,
    const float* __restrict__ att_src, const float* __restrict__ att_dst,
    float* __restrict__ g, float* __restrict__ a_src, float* __restrict__ a_dst,
    int N) {
  __shared__ float As[16][68];
  __shared__ float Bs[16][68];
  const int tid = threadIdx.x;
  const int tx = tid & 15, ty = tid >> 4;
  const int mblk = blockIdx.x * 64;

  float acc[4][4];
#pragma unroll
  for (int i = 0; i < 4; ++i)
#pragma unroll
    for (int j = 0; j < 4; ++j) acc[i][j] = 0.f;

  const int arow = tid >> 2, acol = (tid & 3) * 4;
  const bool avalid = (mblk + arow) < N;
  const float* aptr = h + (size_t)(mblk + arow) * EMBED + acol;
  const float* bptr = Wg + (size_t)arow * EMBED + acol;

  for (int k0 = 0; k0 < EMBED; k0 += 16) {
    float4 av = avalid ? *(const float4*)(aptr + k0) : make_float4(0.f, 0.f, 0.f, 0.f);
    float4 bv = *(const float4*)(bptr + k0);
    __syncthreads();
    As[acol + 0][arow] = av.x;
    As[acol + 1][arow] = av.y;
    As[acol + 2][arow] = av.z;
    As[acol + 3][arow] = av.w;
    Bs[acol + 0][arow] = bv.x;
    Bs[acol + 1][arow] = bv.y;
    Bs[acol + 2][arow] = bv.z;
    Bs[acol + 3][arow] = bv.w;
    __syncthreads();
#pragma unroll
    for (int k = 0; k < 16; ++k) {
      float4 a = *(const float4*)&As[k][ty * 4];
      float4 b = *(const float4*)&Bs[k][tx * 4];
      float am[4] = {a.x, a.y, a.z, a.w};
      float bm[4] = {b.x, b.y, b.z, b.w};
#pragma unroll
      for (int i = 0; i < 4; ++i)
#pragma unroll
        for (int j = 0; j < 4; ++j) acc[i][j] += am[i] * bm[j];
    }
  }

  const int c0 = tx * 4;
  float as_[4], ad_[4];
#pragma unroll
  for (int j = 0; j < 4; ++j) {
    as_[j] = att_src[c0 + j];
    ad_[j] = att_dst[c0 + j];
  }
#pragma unroll
  for (int i = 0; i < 4; ++i) {
    int m = mblk + ty * 4 + i;
    float ps = acc[i][0] * as_[0] + acc[i][1] * as_[1] + acc[i][2] * as_[2] + acc[i][3] * as_[3];
    float pd = acc[i][0] * ad_[0] + acc[i][1] * ad_[1] + acc[i][2] * ad_[2] + acc[i][3] * ad_[3];
#pragma unroll
    for (int d = 1; d < 16; d <<= 1) {
      ps += __shfl_xor(ps, d, 64);
      pd += __shfl_xor(pd, d, 64);
    }
    if (m < N) {
      *(float4*)&g[(size_t)m * OUT_DIM + c0] =
          make_float4(acc[i][0], acc[i][1], acc[i][2], acc[i][3]);
      if (tx == 0) {
        a_src[m] = ps;
        a_dst[m] = pd;
      }
    }
  }
}

// ---------------------------------------------------------------------------
// Edge-phase kernels
// ---------------------------------------------------------------------------
__global__ void zero_kernel(int* __restrict__ p, int n) {
  int i = blockIdx.x * blockDim.x + threadIdx.x;
  if (i < n) p[i] = 0;
}

__global__ void hist_kernel(const int* __restrict__ ei, int* __restrict__ counts,
                            int E, int N) {
  int i = blockIdx.x * blockDim.x + threadIdx.x;
  if (i < E + N) {
    int d = (i < E) ? ei[E + i] : (i - E);
    atomicAdd(&counts[d], 1);
  }
}

// single-block exclusive scan, int4 per thread (4096 elems/iter)
__global__ __launch_bounds__(1024) void scan_kernel(const int4* __restrict__ counts4,
                                                    int* __restrict__ offsets,
                                                    int* __restrict__ next,
                                                    int n4, int n) {
  __shared__ int warp_tot[16];
  __shared__ int warp_scan[16];
  const int tid = threadIdx.x;
  const int lane = tid & 63, w = tid >> 6;
  int carry = 0;
  for (int base = 0; base < n4; base += 1024) {
    int i = base + tid;
    int4 v = (i < n4) ? counts4[i] : make_int4(0, 0, 0, 0);
    int t0 = v.x, t1 = t0 + v.y, t2 = t1 + v.z, t3 = t2 + v.w;
    int incl = t3;
#pragma unroll
    for (int d = 1; d < 64; d <<= 1) {
      int t = __shfl_up(incl, d, 64);
      if (lane >= d) incl += t;
    }
    if (lane == 63) warp_tot[w] = incl;
    __syncthreads();
    if (w == 0) {
      int sc = (lane < 16) ? warp_tot[lane] : 0;
#pragma unroll
      for (int d = 1; d < 16; d <<= 1) {
        int u = __shfl_up(sc, d, 64);
        if (lane >= d) sc += u;
      }
      if (lane < 16) warp_scan[lane] = sc;
    }
    __syncthreads();
    int woff = (w > 0) ? warp_scan[w - 1] : 0;
    int excl = carry + woff + incl - t3;
    if (i < n4) {
      int4 o = make_int4(excl, excl + t0, excl + t1, excl + t2);
      *(int4*)&offsets[4 * i] = o;
      *(int4*)&next[4 * i] = o;
    }
    carry += warp_scan[15];
    __syncthreads();
  }
  if (tid == 0) offsets[n] = carry;
}

// packed record: .x = src index, .y = float bits of edge logit e
__global__ void scatter_kernel(const int* __restrict__ ei,
                               const float* __restrict__ a_src,
                               const float* __restrict__ a_dst,
                               int* __restrict__ next, int2* __restrict__ csr_pack,
                               int E, int N) {
  int i = blockIdx.x * blockDim.x + threadIdx.x;
  if (i < E + N) {
    int s, d;
    if (i < E) {
      s = ei[i];
      d = ei[E + i];
    } else {
      s = d = i - E;
    }
    float e = a_src[s] + a_dst[d];
    e = e > 0.f ? e : 0.2f * e;  // leaky_relu(0.2)
    int pos = atomicAdd(&next[d], 1);
    int2 rec;
    rec.x = s;
    rec.y = __float_as_int(e);
    csr_pack[pos] = rec;  // single 8B store => one dirty line per edge
  }
}

// ---------------------------------------------------------------------------
// one wave per node, lane = output dim.
// Pass 1/2: lane-parallel max & denom over the node's edges.
// Pass 3: chunk-of-64 — lane j holds alpha_j/src_j, broadcast via readlane;
// 4 independent accumulators break the FMA chain.
// ---------------------------------------------------------------------------
__global__ __launch_bounds__(256) void aggregate_kernel(
    const int* __restrict__ offsets, const int2* __restrict__ csr_pack,
    const float* __restrict__ g, const float* __restrict__ b_gat,
    float* __restrict__ out, int N) {
  const int lane = threadIdx.x & 63;
  const int node = blockIdx.x * 4 + (threadIdx.x >> 6);
  if (node >= N) return;
  const int beg = offsets[node], end = offsets[node + 1];

  // pass 1: max
  float m = -1e30f;
  for (int j = beg + lane; j < end; j += 64)
    m = fmaxf(m, __int_as_float(csr_pack[j].y));
#pragma unroll
  for (int d = 1; d < 64; d <<= 1) m = fmaxf(m, __shfl_xor(m, d, 64));

  // pass 2: denom
  float l = 0.f;
  for (int j = beg + lane; j < end; j += 64)
    l += __expf(__int_as_float(csr_pack[j].y) - m);
#pragma unroll
  for (int d = 1; d < 64; d <<= 1) l += __shfl_xor(l, d, 64);
  const float inv_l = 1.f / l;

  // pass 3: aggregate
  float acc0 = 0.f, acc1 = 0.f, acc2 = 0.f, acc3 = 0.f;
  for (int jb = beg; jb < end; jb += 64) {
    int j = jb + lane;
    float p = 0.f;
    int s = 0;
    if (j < end) {
      int2 rec = csr_pack[j];
      p = __expf(__int_as_float(rec.y) - m) * inv_l;
      s = rec.x;
    }
    const int cnt = min(64, end - jb);
    int jj = 0;
    for (; jj + 4 <= cnt; jj += 4) {
      int s0 = __builtin_amdgcn_readlane(s, jj);
      int s1 = __builtin_amdgcn_readlane(s, jj + 1);
      int s2 = __builtin_amdgcn_readlane(s, jj + 2);
      int s3 = __builtin_amdgcn_readlane(s, jj + 3);
      float p0 = readlane_f(p, jj);
      float p1 = readlane_f(p, jj + 1);
      float p2 = readlane_f(p, jj + 2);
      float p3 = readlane_f(p, jj + 3);
      acc0 += p0 * g[((size_t)s0 << 6) + lane];
      acc1 += p1 * g[((size_t)s1 << 6) + lane];
      acc2 += p2 * g[((size_t)s2 << 6) + lane];
      acc3 += p3 * g[((size_t)s3 << 6) + lane];
    }
    for (; jj < cnt; ++jj) {
      int s0 = __builtin_amdgcn_readlane(s, jj);
      float p0 = readlane_f(p, jj);
      acc0 += p0 * g[((size_t)s0 << 6) + lane];
    }
  }
  out[(size_t)node * OUT_DIM + lane] = (acc0 + acc1) + (acc2 + acc3) + b_gat[lane];
}

// ---------------------------------------------------------------------------
extern "C" void kernel_launch(void* const* d_in, const int* in_sizes, int n_in,
                              void* d_out, int out_size, void* d_ws, size_t ws_size,
                              hipStream_t stream) {
  const float* x = (const float*)d_in[0];
  const int* ei = (const int*)d_in[1];
  const float* Wd = (const float*)d_in[2];
  const float* bd = (const float*)d_in[3];
  const float* Wg = (const float*)d_in[4];
  const float* att_src = (const float*)d_in[5];
  const float* att_dst = (const float*)d_in[6];
  const float* bg = (const float*)d_in[7];
  float* out = (float*)d_out;

  const int N = in_sizes[0] / IN_DIM;
  const int E = in_sizes[1] / 2;
  const int T = E + N;

  char* ws = (char*)d_ws;
  size_t off = 0;
  auto alloc = [&](size_t bytes) -> void* {
    void* p = ws + off;
    off += (bytes + 15) & ~(size_t)15;
    return p;
  };
  float* h = (float*)alloc((size_t)N * EMBED * 4);
  float* g = (float*)alloc((size_t)N * OUT_DIM * 4);
  float* a_src = (float*)alloc((size_t)N * 4);
  float* a_dst = (float*)alloc((size_t)N * 4);
  int* counts = (int*)alloc((size_t)N * 4);
  int* offsets = (int*)alloc((size_t)(N + 1) * 4);
  int* next = (int*)alloc((size_t)N * 4);
  int2* csr_pack = (int2*)alloc((size_t)T * 8);

  hipLaunchKernelGGL(gemm1_kernel, dim3((N + 63) / 64), dim3(256), 0, stream,
                     x, Wd, bd, h, N);
  hipLaunchKernelGGL(gemm2_kernel, dim3((N + 63) / 64), dim3(256), 0, stream,
                     h, Wg, att_src, att_dst, g, a_src, a_dst, N);
  hipLaunchKernelGGL(zero_kernel, dim3((N + 255) / 256), dim3(256), 0, stream,
                     counts, N);
  hipLaunchKernelGGL(hist_kernel, dim3((T + 255) / 256), dim3(256), 0, stream,
                     ei, counts, E, N);
  hipLaunchKernelGGL(scan_kernel, dim3(1), dim3(1024), 0, stream,
                     (const int4*)counts, offsets, next, N / 4, N);
  hipLaunchKernelGGL(scatter_kernel, dim3((T + 255) / 256), dim3(256), 0, stream,
                     ei, a_src, a_dst, next, csr_pack, E, N);
  hipLaunchKernelGGL(aggregate_kernel, dim3((N + 3) / 4), dim3(256), 0, stream,
                     offsets, csr_pack, g, bg, out, N);
}

// Round 4
// 427.676 us; speedup vs baseline: 1.4693x; 1.1303x over previous
//
#include <hip/hip_runtime.h>
#include <math.h>

#define IN_DIM 512
#define EMBED 128
#define OUT_DIM 64

typedef __attribute__((ext_vector_type(8))) short bf16x8;
typedef __attribute__((ext_vector_type(4))) float f32x4;

__device__ __forceinline__ float lrelu(float v, float s) { return v > 0.f ? v : v * s; }

__device__ __forceinline__ float readlane_f(float v, int l) {
  return __int_as_float(__builtin_amdgcn_readlane(__float_as_int(v), l));
}

__device__ __forceinline__ unsigned short f2bf(float f) {
  unsigned int u = __float_as_uint(f);
  u += 0x7fff + ((u >> 16) & 1);  // RTNE
  return (unsigned short)(u >> 16);
}
__device__ __forceinline__ float bf2f(unsigned short h) {
  return __uint_as_float(((unsigned int)h) << 16);
}

// ---------------------------------------------------------------------------
// K1 (MFMA split-bf16): h = leaky_relu(x @ Wd^T + bd, 0.01)
// x: [N,512] fp32, Wd: [128,512] fp32. v = hi+lo bf16 split;
// A*B = Ah*Bh + Al*Bh + Ah*Bl (fp32-class accuracy, err ~2^-18).
// Block tile 128x64, 4 waves of 64x32, mfma_f32_16x16x32_bf16.
// LDS stride 40 bf16 (80B): frag b128 reads 2-way aliased (free, m136).
// ---------------------------------------------------------------------------
#define LDA 40

__global__ __launch_bounds__(256) void gemm1_mfma_kernel(
    const float* __restrict__ x, const float* __restrict__ Wd,
    const float* __restrict__ bd, float* __restrict__ h, int N) {
  __shared__ __align__(16) unsigned short Ah[128][LDA];
  __shared__ __align__(16) unsigned short Al[128][LDA];
  __shared__ __align__(16) unsigned short Bh[64][LDA];
  __shared__ __align__(16) unsigned short Bl[64][LDA];

  const int tid = threadIdx.x;
  const int lane = tid & 63;
  const int wid = tid >> 6;
  const int wr = wid >> 1, wc = wid & 1;  // wave: m half, n half
  const int mblk = blockIdx.x * 128;
  const int nblk = blockIdx.y * 64;
  const int quad = lane >> 4;
  const int l15 = lane & 15;

  // staging: A 128 rows x 32 k (16 floats/thread), B 64 rows x 32 k (8/thread)
  const int arow = tid >> 1, acb = (tid & 1) * 16;
  const int brow = tid >> 2, bcb = (tid & 3) * 8;
  const bool avalid = (mblk + arow) < N;
  const float* aptr = x + (size_t)(mblk + arow) * IN_DIM + acb;
  const float* bptr = Wd + (size_t)(nblk + brow) * IN_DIM + bcb;

  f32x4 acc[4][2];
#pragma unroll
  for (int i = 0; i < 4; ++i)
#pragma unroll
    for (int j = 0; j < 2; ++j) acc[i][j] = (f32x4){0.f, 0.f, 0.f, 0.f};

  for (int k0 = 0; k0 < IN_DIM; k0 += 32) {
    float4 t0, t1, t2, t3;
    if (avalid) {
      t0 = *(const float4*)(aptr + k0);
      t1 = *(const float4*)(aptr + k0 + 4);
      t2 = *(const float4*)(aptr + k0 + 8);
      t3 = *(const float4*)(aptr + k0 + 12);
    } else {
      t0 = t1 = t2 = t3 = make_float4(0.f, 0.f, 0.f, 0.f);
    }
    float4 u0 = *(const float4*)(bptr + k0);
    float4 u1 = *(const float4*)(bptr + k0 + 4);

    float av[16] = {t0.x, t0.y, t0.z, t0.w, t1.x, t1.y, t1.z, t1.w,
                    t2.x, t2.y, t2.z, t2.w, t3.x, t3.y, t3.z, t3.w};
    union { unsigned short us[16]; uint4 v[2]; } AH, AL;
#pragma unroll
    for (int i = 0; i < 16; ++i) {
      unsigned short hi = f2bf(av[i]);
      AH.us[i] = hi;
      AL.us[i] = f2bf(av[i] - bf2f(hi));
    }
    float bv[8] = {u0.x, u0.y, u0.z, u0.w, u1.x, u1.y, u1.z, u1.w};
    union { unsigned short us[8]; uint4 v; } BH, BL;
#pragma unroll
    for (int i = 0; i < 8; ++i) {
      unsigned short hi = f2bf(bv[i]);
      BH.us[i] = hi;
      BL.us[i] = f2bf(bv[i] - bf2f(hi));
    }

    __syncthreads();  // previous iter's frag reads done
    *(uint4*)&Ah[arow][acb] = AH.v[0];
    *(uint4*)&Ah[arow][acb + 8] = AH.v[1];
    *(uint4*)&Al[arow][acb] = AL.v[0];
    *(uint4*)&Al[arow][acb + 8] = AL.v[1];
    *(uint4*)&Bh[brow][bcb] = BH.v;
    *(uint4*)&Bl[brow][bcb] = BL.v;
    __syncthreads();

    bf16x8 ah[4], al[4], bh[2], bl[2];
#pragma unroll
    for (int mi = 0; mi < 4; ++mi) {
      int r = wr * 64 + mi * 16 + l15;
      ah[mi] = *(const bf16x8*)&Ah[r][quad * 8];
      al[mi] = *(const bf16x8*)&Al[r][quad * 8];
    }
#pragma unroll
    for (int ni = 0; ni < 2; ++ni) {
      int r = wc * 32 + ni * 16 + l15;
      bh[ni] = *(const bf16x8*)&Bh[r][quad * 8];
      bl[ni] = *(const bf16x8*)&Bl[r][quad * 8];
    }
#pragma unroll
    for (int mi = 0; mi < 4; ++mi)
#pragma unroll
      for (int ni = 0; ni < 2; ++ni) {
        acc[mi][ni] = __builtin_amdgcn_mfma_f32_16x16x32_bf16(ah[mi], bh[ni], acc[mi][ni], 0, 0, 0);
        acc[mi][ni] = __builtin_amdgcn_mfma_f32_16x16x32_bf16(al[mi], bh[ni], acc[mi][ni], 0, 0, 0);
        acc[mi][ni] = __builtin_amdgcn_mfma_f32_16x16x32_bf16(ah[mi], bl[ni], acc[mi][ni], 0, 0, 0);
      }
  }

#pragma unroll
  for (int mi = 0; mi < 4; ++mi)
#pragma unroll
    for (int ni = 0; ni < 2; ++ni) {
      int n = nblk + wc * 32 + ni * 16 + l15;
      float b = bd[n];
#pragma unroll
      for (int r = 0; r < 4; ++r) {
        int m = mblk + wr * 64 + mi * 16 + quad * 4 + r;
        if (m < N) h[(size_t)m * EMBED + n] = lrelu(acc[mi][ni][r] + b, 0.01f);
      }
    }
}

// ---------------------------------------------------------------------------
// K2: g = h @ Wg^T ; a_src = g@att_src ; a_dst = g@att_dst
// ---------------------------------------------------------------------------
__global__ __launch_bounds__(256) void gemm2_kernel(
    const float* __restrict__ h, const float* __restrict__ Wg,
    const float* __restrict__ att_src, const float* __restrict__ att_dst,
    float* __restrict__ g, float* __restrict__ a_src, float* __restrict__ a_dst,
    int N) {
  __shared__ float As[16][68];
  __shared__ float Bs[16][68];
  const int tid = threadIdx.x;
  const int tx = tid & 15, ty = tid >> 4;
  const int mblk = blockIdx.x * 64;

  float acc[4][4];
#pragma unroll
  for (int i = 0; i < 4; ++i)
#pragma unroll
    for (int j = 0; j < 4; ++j) acc[i][j] = 0.f;

  const int arow = tid >> 2, acol = (tid & 3) * 4;
  const bool avalid = (mblk + arow) < N;
  const float* aptr = h + (size_t)(mblk + arow) * EMBED + acol;
  const float* bptr = Wg + (size_t)arow * EMBED + acol;

  for (int k0 = 0; k0 < EMBED; k0 += 16) {
    float4 av = avalid ? *(const float4*)(aptr + k0) : make_float4(0.f, 0.f, 0.f, 0.f);
    float4 bv = *(const float4*)(bptr + k0);
    __syncthreads();
    As[acol + 0][arow] = av.x;
    As[acol + 1][arow] = av.y;
    As[acol + 2][arow] = av.z;
    As[acol + 3][arow] = av.w;
    Bs[acol + 0][arow] = bv.x;
    Bs[acol + 1][arow] = bv.y;
    Bs[acol + 2][arow] = bv.z;
    Bs[acol + 3][arow] = bv.w;
    __syncthreads();
#pragma unroll
    for (int k = 0; k < 16; ++k) {
      float4 a = *(const float4*)&As[k][ty * 4];
      float4 b = *(const float4*)&Bs[k][tx * 4];
      float am[4] = {a.x, a.y, a.z, a.w};
      float bm[4] = {b.x, b.y, b.z, b.w};
#pragma unroll
      for (int i = 0; i < 4; ++i)
#pragma unroll
        for (int j = 0; j < 4; ++j) acc[i][j] += am[i] * bm[j];
    }
  }

  const int c0 = tx * 4;
  float as_[4], ad_[4];
#pragma unroll
  for (int j = 0; j < 4; ++j) {
    as_[j] = att_src[c0 + j];
    ad_[j] = att_dst[c0 + j];
  }
#pragma unroll
  for (int i = 0; i < 4; ++i) {
    int m = mblk + ty * 4 + i;
    float ps = acc[i][0] * as_[0] + acc[i][1] * as_[1] + acc[i][2] * as_[2] + acc[i][3] * as_[3];
    float pd = acc[i][0] * ad_[0] + acc[i][1] * ad_[1] + acc[i][2] * ad_[2] + acc[i][3] * ad_[3];
#pragma unroll
    for (int d = 1; d < 16; d <<= 1) {
      ps += __shfl_xor(ps, d, 64);
      pd += __shfl_xor(pd, d, 64);
    }
    if (m < N) {
      *(float4*)&g[(size_t)m * OUT_DIM + c0] =
          make_float4(acc[i][0], acc[i][1], acc[i][2], acc[i][3]);
      if (tx == 0) {
        a_src[m] = ps;
        a_dst[m] = pd;
      }
    }
  }
}

// ---------------------------------------------------------------------------
// Edge-phase kernels
// ---------------------------------------------------------------------------
__global__ void zero_kernel(int* __restrict__ p, int n) {
  int i = blockIdx.x * blockDim.x + threadIdx.x;
  if (i < n) p[i] = 0;
}

__global__ void hist_kernel(const int* __restrict__ ei, int* __restrict__ counts,
                            int E, int N) {
  int i = blockIdx.x * blockDim.x + threadIdx.x;
  if (i < E + N) {
    int d = (i < E) ? ei[E + i] : (i - E);
    atomicAdd(&counts[d], 1);
  }
}

// single-block exclusive scan, int4 per thread (4096 elems/iter)
__global__ __launch_bounds__(1024) void scan_kernel(const int4* __restrict__ counts4,
                                                    int* __restrict__ offsets,
                                                    int* __restrict__ next,
                                                    int n4, int n) {
  __shared__ int warp_tot[16];
  __shared__ int warp_scan[16];
  const int tid = threadIdx.x;
  const int lane = tid & 63, w = tid >> 6;
  int carry = 0;
  for (int base = 0; base < n4; base += 1024) {
    int i = base + tid;
    int4 v = (i < n4) ? counts4[i] : make_int4(0, 0, 0, 0);
    int t0 = v.x, t1 = t0 + v.y, t2 = t1 + v.z, t3 = t2 + v.w;
    int incl = t3;
#pragma unroll
    for (int d = 1; d < 64; d <<= 1) {
      int t = __shfl_up(incl, d, 64);
      if (lane >= d) incl += t;
    }
    if (lane == 63) warp_tot[w] = incl;
    __syncthreads();
    if (w == 0) {
      int sc = (lane < 16) ? warp_tot[lane] : 0;
#pragma unroll
      for (int d = 1; d < 16; d <<= 1) {
        int u = __shfl_up(sc, d, 64);
        if (lane >= d) sc += u;
      }
      if (lane < 16) warp_scan[lane] = sc;
    }
    __syncthreads();
    int woff = (w > 0) ? warp_scan[w - 1] : 0;
    int excl = carry + woff + incl - t3;
    if (i < n4) {
      int4 o = make_int4(excl, excl + t0, excl + t1, excl + t2);
      *(int4*)&offsets[4 * i] = o;
      *(int4*)&next[4 * i] = o;
    }
    carry += warp_scan[15];
    __syncthreads();
  }
  if (tid == 0) offsets[n] = carry;
}

// packed record: .x = src index, .y = float bits of edge logit e
__global__ void scatter_kernel(const int* __restrict__ ei,
                               const float* __restrict__ a_src,
                               const float* __restrict__ a_dst,
                               int* __restrict__ next, int2* __restrict__ csr_pack,
                               int E, int N) {
  int i = blockIdx.x * blockDim.x + threadIdx.x;
  if (i < E + N) {
    int s, d;
    if (i < E) {
      s = ei[i];
      d = ei[E + i];
    } else {
      s = d = i - E;
    }
    float e = a_src[s] + a_dst[d];
    e = e > 0.f ? e : 0.2f * e;  // leaky_relu(0.2)
    int pos = atomicAdd(&next[d], 1);
    int2 rec;
    rec.x = s;
    rec.y = __float_as_int(e);
    csr_pack[pos] = rec;
  }
}

// ---------------------------------------------------------------------------
// one wave per node, lane = output dim; readlane-broadcast aggregation
// ---------------------------------------------------------------------------
__global__ __launch_bounds__(256) void aggregate_kernel(
    const int* __restrict__ offsets, const int2* __restrict__ csr_pack,
    const float* __restrict__ g, const float* __restrict__ b_gat,
    float* __restrict__ out, int N) {
  const int lane = threadIdx.x & 63;
  const int node = blockIdx.x * 4 + (threadIdx.x >> 6);
  if (node >= N) return;
  const int beg = offsets[node], end = offsets[node + 1];

  float m = -1e30f;
  for (int j = beg + lane; j < end; j += 64)
    m = fmaxf(m, __int_as_float(csr_pack[j].y));
#pragma unroll
  for (int d = 1; d < 64; d <<= 1) m = fmaxf(m, __shfl_xor(m, d, 64));

  float l = 0.f;
  for (int j = beg + lane; j < end; j += 64)
    l += __expf(__int_as_float(csr_pack[j].y) - m);
#pragma unroll
  for (int d = 1; d < 64; d <<= 1) l += __shfl_xor(l, d, 64);
  const float inv_l = 1.f / l;

  float acc0 = 0.f, acc1 = 0.f, acc2 = 0.f, acc3 = 0.f;
  for (int jb = beg; jb < end; jb += 64) {
    int j = jb + lane;
    float p = 0.f;
    int s = 0;
    if (j < end) {
      int2 rec = csr_pack[j];
      p = __expf(__int_as_float(rec.y) - m) * inv_l;
      s = rec.x;
    }
    const int cnt = min(64, end - jb);
    int jj = 0;
    for (; jj + 4 <= cnt; jj += 4) {
      int s0 = __builtin_amdgcn_readlane(s, jj);
      int s1 = __builtin_amdgcn_readlane(s, jj + 1);
      int s2 = __builtin_amdgcn_readlane(s, jj + 2);
      int s3 = __builtin_amdgcn_readlane(s, jj + 3);
      float p0 = readlane_f(p, jj);
      float p1 = readlane_f(p, jj + 1);
      float p2 = readlane_f(p, jj + 2);
      float p3 = readlane_f(p, jj + 3);
      acc0 += p0 * g[((size_t)s0 << 6) + lane];
      acc1 += p1 * g[((size_t)s1 << 6) + lane];
      acc2 += p2 * g[((size_t)s2 << 6) + lane];
      acc3 += p3 * g[((size_t)s3 << 6) + lane];
    }
    for (; jj < cnt; ++jj) {
      int s0 = __builtin_amdgcn_readlane(s, jj);
      float p0 = readlane_f(p, jj);
      acc0 += p0 * g[((size_t)s0 << 6) + lane];
    }
  }
  out[(size_t)node * OUT_DIM + lane] = (acc0 + acc1) + (acc2 + acc3) + b_gat[lane];
}

// ---------------------------------------------------------------------------
extern "C" void kernel_launch(void* const* d_in, const int* in_sizes, int n_in,
                              void* d_out, int out_size, void* d_ws, size_t ws_size,
                              hipStream_t stream) {
  const float* x = (const float*)d_in[0];
  const int* ei = (const int*)d_in[1];
  const float* Wd = (const float*)d_in[2];
  const float* bd = (const float*)d_in[3];
  const float* Wg = (const float*)d_in[4];
  const float* att_src = (const float*)d_in[5];
  const float* att_dst = (const float*)d_in[6];
  const float* bg = (const float*)d_in[7];
  float* out = (float*)d_out;

  const int N = in_sizes[0] / IN_DIM;
  const int E = in_sizes[1] / 2;
  const int T = E + N;

  char* ws = (char*)d_ws;
  size_t off = 0;
  auto alloc = [&](size_t bytes) -> void* {
    void* p = ws + off;
    off += (bytes + 15) & ~(size_t)15;
    return p;
  };
  float* h = (float*)alloc((size_t)N * EMBED * 4);
  float* g = (float*)alloc((size_t)N * OUT_DIM * 4);
  float* a_src = (float*)alloc((size_t)N * 4);
  float* a_dst = (float*)alloc((size_t)N * 4);
  int* counts = (int*)alloc((size_t)N * 4);
  int* offsets = (int*)alloc((size_t)(N + 1) * 4);
  int* next = (int*)alloc((size_t)N * 4);
  int2* csr_pack = (int2*)alloc((size_t)T * 8);

  hipLaunchKernelGGL(gemm1_mfma_kernel, dim3((N + 127) / 128, 2), dim3(256), 0,
                     stream, x, Wd, bd, h, N);
  hipLaunchKernelGGL(gemm2_kernel, dim3((N + 63) / 64), dim3(256), 0, stream,
                     h, Wg, att_src, att_dst, g, a_src, a_dst, N);
  hipLaunchKernelGGL(zero_kernel, dim3((N + 255) / 256), dim3(256), 0, stream,
                     counts, N);
  hipLaunchKernelGGL(hist_kernel, dim3((T + 255) / 256), dim3(256), 0, stream,
                     ei, counts, E, N);
  hipLaunchKernelGGL(scan_kernel, dim3(1), dim3(1024), 0, stream,
                     (const int4*)counts, offsets, next, N / 4, N);
  hipLaunchKernelGGL(scatter_kernel, dim3((T + 255) / 256), dim3(256), 0, stream,
                     ei, a_src, a_dst, next, csr_pack, E, N);
  hipLaunchKernelGGL(aggregate_kernel, dim3((N + 3) / 4), dim3(256), 0, stream,
                     offsets, csr_pack, g, bg, out, N);
}